// Round 11
// baseline (246.709 us; speedup 1.0000x reference)
//
#include <hip/hip_runtime.h>

#define KNN_INF 3.0e38f

// ================== kNN: r5-proven (all 4 stages, LDS-staged, branchy) ==================
struct KnnAll {
    const float* p1[4]; const float* p2[4];
    float* pd[4]; int* pi[4];
    int N1[4], N2[4], chunk[4], nchunk[4], nbx[4];
    int bs1, bs2, bs3;
};

__global__ void knn_all_kernel(KnnAll P) {
    __shared__ float4 sm4[256];
    int bid = blockIdx.x;
    int s = (bid >= P.bs1) + (bid >= P.bs2) + (bid >= P.bs3);
    int start = (s == 0) ? 0 : (s == 1) ? P.bs1 : (s == 2) ? P.bs2 : P.bs3;
    int local = bid - start;
    int nbx = P.nbx[s];
    int bx = local % nbx;
    int rest = local / nbx;
    int b = rest & 7;          // B == 8
    int z = rest >> 3;
    int N1 = P.N1[s], N2 = P.N2[s], chunk = P.chunk[s], nchunk = P.nchunk[s];
    int m0 = z * chunk;
    const float* p2b = P.p2[s] + ((size_t)b * N2 + m0) * 3;
    for (int m = threadIdx.x; m < chunk; m += blockDim.x) {
        float x = p2b[m * 3 + 0], y = p2b[m * 3 + 1], zz = p2b[m * 3 + 2];
        sm4[m] = make_float4(x, y, zz, x * x + y * y + zz * zz);
    }
    __syncthreads();
    int n = bx * blockDim.x + threadIdx.x;
    if (n >= N1) return;
    const float* p1b = P.p1[s] + ((size_t)b * N1 + n) * 3;
    float px = p1b[0], py = p1b[1], pz = p1b[2];
    float s1 = px * px + py * py + pz * pz;
    float d0 = KNN_INF, d1 = KNN_INF, d2 = KNN_INF;
    int i0 = 0, i1 = 0, i2 = 0;
    for (int m = 0; m < chunk; ++m) {
        float4 q = sm4[m];
        float dot = px * q.x + py * q.y + pz * q.z;
        float d = fmaf(-2.0f, dot, s1 + q.w);
        if (d < d2) {
            if (d < d1) {
                d2 = d1; i2 = i1;
                if (d < d0) { d1 = d0; i1 = i0; d0 = d; i0 = m; }
                else        { d1 = d;  i1 = m; }
            } else { d2 = d; i2 = m; }
        }
    }
    size_t base = (((size_t)b * N1 + n) * nchunk + z) * 3;
    float* pd = P.pd[s]; int* pi = P.pi[s];
    pd[base + 0] = d0; pd[base + 1] = d1; pd[base + 2] = d2;
    pi[base + 0] = m0 + i0; pi[base + 1] = m0 + i1; pi[base + 2] = m0 + i2;
}

struct MergeAll {
    const float* pd[4]; const int* pi[4];
    int* idx[4]; float* w[4];
    int nchunk[4];
    int ts1, ts2, ts3;
};

__global__ void knn_merge_all_kernel(MergeAll P, int total) {
    int t = blockIdx.x * blockDim.x + threadIdx.x;
    if (t >= total) return;
    int s = (t >= P.ts1) + (t >= P.ts2) + (t >= P.ts3);
    int start = (s == 0) ? 0 : (s == 1) ? P.ts1 : (s == 2) ? P.ts2 : P.ts3;
    int lt = t - start;
    int nchunk = P.nchunk[s];
    float d0 = KNN_INF, d1 = KNN_INF, d2 = KNN_INF;
    int i0 = 0, i1 = 0, i2 = 0;
    const float* pd = P.pd[s]; const int* pi = P.pi[s];
    size_t base = (size_t)lt * nchunk * 3;
    for (int c = 0; c < nchunk * 3; ++c) {
        float d = pd[base + c];
        int   i = pi[base + c];
        if (d < d2) {
            if (d < d1) {
                d2 = d1; i2 = i1;
                if (d < d0) { d1 = d0; i1 = i0; d0 = d; i0 = i; }
                else        { d1 = d;  i1 = i; }
            } else { d2 = d; i2 = i; }
        }
    }
    float dd0 = fmaxf(d0, 0.0f), dd1 = fmaxf(d1, 0.0f), dd2 = fmaxf(d2, 0.0f);
    float w0 = 1.0f / (dd0 + 1e-8f);
    float w1 = 1.0f / (dd1 + 1e-8f);
    float w2 = 1.0f / (dd2 + 1e-8f);
    float wsum = w0 + w1 + w2;
    w0 /= wsum; w1 /= wsum; w2 /= wsum;
    size_t ob = (size_t)lt * 3;
    P.idx[s][ob + 0] = i0; P.idx[s][ob + 1] = i1; P.idx[s][ob + 2] = i2;
    P.w[s][ob + 0] = w0; P.w[s][ob + 1] = w1; P.w[s][ob + 2] = w2;
}

// ================== conv kernels: 16 outputs/thread register tiles ==================
#define BK 16

// ---- conv_a (gather-fused), split-K capable ----
template<int TOc, int TNc, int RO, int RN, bool PARTIAL>
__global__ __launch_bounds__(256) void conv_a_tiled(
    const float* __restrict__ f1, const float* __restrict__ x2,
    const int* __restrict__ idxS, const float* __restrict__ wS,
    const float* __restrict__ W, const float* __restrict__ g, const float* __restrict__ bv,
    float* __restrict__ Y,
    int C1, int C2, int N, int N2, int Cout, int chunk) {
    __shared__ float Ws[BK][TOc];
    __shared__ float Xs[BK][TNc];
    constexpr int TX = TNc / RN;       // threads along n
    constexpr int RPP = 256 / TNc;     // k-rows staged per pass
    int Cin = C1 + C2;
    int zb = blockIdx.z;
    int b = zb & 7;
    int split = zb >> 3;
    int kBase = split * chunk;
    int oBase = blockIdx.y * TOc;
    int nBase = blockIdx.x * TNc;
    int tid = threadIdx.x;
    int tx = tid % TX;
    int ty = tid / TX;
    int nn = tid % TNc;
    int kr0 = tid / TNc;
    int n = nBase + nn;
    size_t gb = ((size_t)b * N + n) * 3;
    int j0 = idxS[gb + 0], j1 = idxS[gb + 1], j2 = idxS[gb + 2];
    float w0g = wS[gb + 0], w1g = wS[gb + 1], w2g = wS[gb + 2];
    const float* f1b = f1 + (size_t)b * C1 * N;
    const float* x2b = x2 + (size_t)b * C2 * N2;
    float acc[RO][RN] = {};
    for (int k0 = kBase; k0 < kBase + chunk; k0 += BK) {
        // W stage: o-major (conflict-free LDS writes)
        for (int t = tid; t < TOc * BK; t += 256) {
            int o = t % TOc, kk = t / TOc;
            Ws[kk][o] = W[(size_t)(oBase + o) * Cin + k0 + kk];
        }
        // X stage: gather-fused
#pragma unroll
        for (int i = 0; i < BK / RPP; ++i) {
            int kk = kr0 + i * RPP;
            int k = k0 + kk;
            float v;
            if (k < C1) {
                v = f1b[(size_t)k * N + n];
            } else {
                const float* r = x2b + (size_t)(k - C1) * N2;
                v = r[j0] * w0g + r[j1] * w1g + r[j2] * w2g;
            }
            Xs[kk][nn] = v;
        }
        __syncthreads();
#pragma unroll
        for (int kk = 0; kk < BK; ++kk) {
            float wv[RO], xv[RN];
#pragma unroll
            for (int r = 0; r < RO; ++r) wv[r] = Ws[kk][ty * RO + r];
#pragma unroll
            for (int c4 = 0; c4 < RN / 4; ++c4) {
                float4 x4 = *reinterpret_cast<const float4*>(&Xs[kk][tx * RN + c4 * 4]);
                xv[c4 * 4 + 0] = x4.x; xv[c4 * 4 + 1] = x4.y;
                xv[c4 * 4 + 2] = x4.z; xv[c4 * 4 + 3] = x4.w;
            }
#pragma unroll
            for (int r = 0; r < RO; ++r)
#pragma unroll
                for (int c = 0; c < RN; ++c)
                    acc[r][c] = fmaf(wv[r], xv[c], acc[r][c]);
        }
        __syncthreads();
    }
#pragma unroll
    for (int r = 0; r < RO; ++r) {
        int o = oBase + ty * RO + r;
        if (PARTIAL) {
            float* dst = &Y[((size_t)zb * Cout + o) * N + nBase + tx * RN];
#pragma unroll
            for (int c4 = 0; c4 < RN / 4; ++c4) {
                float4 st = make_float4(acc[r][c4 * 4 + 0], acc[r][c4 * 4 + 1],
                                        acc[r][c4 * 4 + 2], acc[r][c4 * 4 + 3]);
                *reinterpret_cast<float4*>(dst + c4 * 4) = st;
            }
        } else {
            float gg = g[o], bb = bv[o];
            float* dst = &Y[((size_t)b * Cout + o) * N + nBase + tx * RN];
#pragma unroll
            for (int c4 = 0; c4 < RN / 4; ++c4) {
                float4 st;
                st.x = fmaxf(fmaf(acc[r][c4 * 4 + 0], gg, bb), 0.0f);
                st.y = fmaxf(fmaf(acc[r][c4 * 4 + 1], gg, bb), 0.0f);
                st.z = fmaxf(fmaf(acc[r][c4 * 4 + 2], gg, bb), 0.0f);
                st.w = fmaxf(fmaf(acc[r][c4 * 4 + 3], gg, bb), 0.0f);
                *reinterpret_cast<float4*>(dst + c4 * 4) = st;
            }
        }
    }
}

// ---- conv_b (plain GEMM), split-K capable ----
template<int TOc, int TNc, int RO, int RN, bool PARTIAL>
__global__ __launch_bounds__(256) void conv_b_tiled(
    const float* __restrict__ X, const float* __restrict__ W,
    const float* __restrict__ g, const float* __restrict__ bv,
    float* __restrict__ Y, int Cin, int Cout, int N, int chunk) {
    __shared__ float Ws[BK][TOc];
    __shared__ float Xs[BK][TNc];
    constexpr int TX = TNc / RN;
    int zb = blockIdx.z;
    int b = zb & 7;
    int split = zb >> 3;
    int kBase = split * chunk;
    int oBase = blockIdx.y * TOc;
    int nBase = blockIdx.x * TNc;
    int tid = threadIdx.x;
    int tx = tid % TX;
    int ty = tid / TX;
    float acc[RO][RN] = {};
    const float* Xb = X + (size_t)b * Cin * N;
    for (int k0 = kBase; k0 < kBase + chunk; k0 += BK) {
        for (int t = tid; t < TOc * BK; t += 256) {
            int o = t % TOc, kk = t / TOc;
            Ws[kk][o] = W[(size_t)(oBase + o) * Cin + k0 + kk];
        }
        for (int t = tid; t < BK * TNc; t += 256) {
            int kk = t / TNc, nnn = t % TNc;
            Xs[kk][nnn] = Xb[(size_t)(k0 + kk) * N + nBase + nnn];
        }
        __syncthreads();
#pragma unroll
        for (int kk = 0; kk < BK; ++kk) {
            float wv[RO], xv[RN];
#pragma unroll
            for (int r = 0; r < RO; ++r) wv[r] = Ws[kk][ty * RO + r];
#pragma unroll
            for (int c4 = 0; c4 < RN / 4; ++c4) {
                float4 x4 = *reinterpret_cast<const float4*>(&Xs[kk][tx * RN + c4 * 4]);
                xv[c4 * 4 + 0] = x4.x; xv[c4 * 4 + 1] = x4.y;
                xv[c4 * 4 + 2] = x4.z; xv[c4 * 4 + 3] = x4.w;
            }
#pragma unroll
            for (int r = 0; r < RO; ++r)
#pragma unroll
                for (int c = 0; c < RN; ++c)
                    acc[r][c] = fmaf(wv[r], xv[c], acc[r][c]);
        }
        __syncthreads();
    }
#pragma unroll
    for (int r = 0; r < RO; ++r) {
        int o = oBase + ty * RO + r;
        if (PARTIAL) {
            float* dst = &Y[((size_t)zb * Cout + o) * N + nBase + tx * RN];
#pragma unroll
            for (int c4 = 0; c4 < RN / 4; ++c4) {
                float4 st = make_float4(acc[r][c4 * 4 + 0], acc[r][c4 * 4 + 1],
                                        acc[r][c4 * 4 + 2], acc[r][c4 * 4 + 3]);
                *reinterpret_cast<float4*>(dst + c4 * 4) = st;
            }
        } else {
            float gg = g[o], bb = bv[o];
            float* dst = &Y[((size_t)b * Cout + o) * N + nBase + tx * RN];
#pragma unroll
            for (int c4 = 0; c4 < RN / 4; ++c4) {
                float4 st;
                st.x = fmaxf(fmaf(acc[r][c4 * 4 + 0], gg, bb), 0.0f);
                st.y = fmaxf(fmaf(acc[r][c4 * 4 + 1], gg, bb), 0.0f);
                st.z = fmaxf(fmaf(acc[r][c4 * 4 + 2], gg, bb), 0.0f);
                st.w = fmaxf(fmaf(acc[r][c4 * 4 + 3], gg, bb), 0.0f);
                *reinterpret_cast<float4*>(dst + c4 * 4) = st;
            }
        }
    }
}

__global__ void reduce_bn_relu_kernel(const float* __restrict__ part,
                                      const float* __restrict__ g,
                                      const float* __restrict__ bv,
                                      float* __restrict__ Y,
                                      int Cout, int N, int total4, int nsplit, int stride4) {
    int t = blockIdx.x * blockDim.x + threadIdx.x;
    if (t >= total4) return;
    const float4* p4 = reinterpret_cast<const float4*>(part);
    float4 a = p4[t];
    for (int s = 1; s < nsplit; ++s) {
        float4 v = p4[t + (size_t)s * stride4];
        a.x += v.x; a.y += v.y; a.z += v.z; a.w += v.w;
    }
    int o = ((t * 4) / N) % Cout;
    float gg = g[o], bb = bv[o];
    float4 st;
    st.x = fmaxf(fmaf(a.x, gg, bb), 0.0f);
    st.y = fmaxf(fmaf(a.y, gg, bb), 0.0f);
    st.z = fmaxf(fmaf(a.z, gg, bb), 0.0f);
    st.w = fmaxf(fmaf(a.w, gg, bb), 0.0f);
    reinterpret_cast<float4*>(Y)[t] = st;
}

extern "C" void kernel_launch(void* const* d_in, const int* in_sizes, int n_in,
                              void* d_out, int out_size, void* d_ws, size_t ws_size,
                              hipStream_t stream) {
    const int B = 8;
    const int Ns[5]  = {8192, 2048, 512, 128, 32};
    const int CHs[5] = {32, 64, 128, 256, 512};

    const float* p[5];
    const float* f[5];
    for (int i = 0; i < 5; ++i) {
        p[i] = (const float*)d_in[2 * i];
        f[i] = (const float*)d_in[2 * i + 1];
    }

    int N1s[4], N2s[4], C1s[4], C2s[4];
    for (int s = 0; s < 4; ++s) {
        int lvl = 3 - s;
        N1s[s] = Ns[lvl]; N2s[s] = Ns[lvl + 1];
        C1s[s] = CHs[lvl];
        C2s[s] = (s == 0) ? CHs[4] : CHs[lvl + 1];
    }
    const int nchunks[4] = {1, 4, 8, 8};
    int chunks[4], nbxs[4];
    for (int s = 0; s < 4; ++s) {
        chunks[s] = N2s[s] / nchunks[s];
        nbxs[s] = (N1s[s] + 255) / 256;
    }

    // ---- workspace layout (floats) — r5-proven ----
    float* ws = (float*)d_ws;
    int*   knn_idx = (int*)ws;                  // 262144
    float* knn_w   = ws + 262144;               // 262144
    float* part_d  = ws + 524288;               // 2018304
    int*   part_i  = (int*)(ws + 2621440);      // 2018304
    float* bufA    = ws + 4718592;              // 2097152
    float* out0    = ws + 6815744;              // 262144
    float* out1    = ws + 7077888;              // 524288
    float* out2    = ws + 7602176;              // 1048576
    float* gpart   = ws + 8650752;              // 1572864 max
    float* outs[4] = {out0, out1, out2, (float*)d_out};

    int idxOff[4], pOff[4];
    {
        int a = 0, q = 0;
        for (int s = 0; s < 4; ++s) {
            idxOff[s] = a; a += B * N1s[s] * 3;
            pOff[s] = q;  q += B * N1s[s] * nchunks[s] * 3;
        }
    }

    // ---- one combined kNN launch for all stages (r5) ----
    KnnAll KP;
    int blk = 0, bsArr[4];
    for (int s = 0; s < 4; ++s) {
        KP.p1[s] = p[3 - s]; KP.p2[s] = p[4 - s];
        KP.pd[s] = part_d + pOff[s]; KP.pi[s] = part_i + pOff[s];
        KP.N1[s] = N1s[s]; KP.N2[s] = N2s[s];
        KP.chunk[s] = chunks[s]; KP.nchunk[s] = nchunks[s]; KP.nbx[s] = nbxs[s];
        bsArr[s] = blk;
        blk += nbxs[s] * B * nchunks[s];
    }
    KP.bs1 = bsArr[1]; KP.bs2 = bsArr[2]; KP.bs3 = bsArr[3];
    knn_all_kernel<<<blk, 256, 0, stream>>>(KP);

    // ---- one combined merge launch (r5) ----
    MergeAll MP;
    int tt = 0, tsArr[4];
    for (int s = 0; s < 4; ++s) {
        MP.pd[s] = part_d + pOff[s]; MP.pi[s] = part_i + pOff[s];
        MP.idx[s] = knn_idx + idxOff[s]; MP.w[s] = knn_w + idxOff[s];
        MP.nchunk[s] = nchunks[s];
        tsArr[s] = tt;
        tt += B * N1s[s];
    }
    MP.ts1 = tsArr[1]; MP.ts2 = tsArr[2]; MP.ts3 = tsArr[3];
    knn_merge_all_kernel<<<(tt + 255) / 256, 256, 0, stream>>>(MP, tt);

    const int nsA[4] = {6, 3, 2, 1};
    const int nsB[4] = {4, 2, 1, 1};

    for (int s = 0; s < 4; ++s) {
        int N1 = N1s[s], N2 = N2s[s];
        int C1 = C1s[s], C2 = C2s[s];
        int Cin = C1 + C2, Cout = C1;
        const float* x2 = (s == 0) ? f[4] : outs[s - 1];
        const float* wa = (const float*)d_in[10 + s * 6 + 0];
        const float* ga = (const float*)d_in[10 + s * 6 + 1];
        const float* ba = (const float*)d_in[10 + s * 6 + 2];
        const float* wb = (const float*)d_in[10 + s * 6 + 3];
        const float* gb = (const float*)d_in[10 + s * 6 + 4];
        const float* bb = (const float*)d_in[10 + s * 6 + 5];
        const int* idxS = knn_idx + idxOff[s];
        const float* wSb = knn_w + idxOff[s];

        if (s == 3) {
            // Cout=32: 32x128 tile, 2x8/thread, no split-K
            dim3 ga_(N1 / 128, 1, B);
            conv_a_tiled<32, 128, 2, 8, false><<<ga_, 256, 0, stream>>>(
                f[3 - s], x2, idxS, wSb, wa, ga, ba, bufA, C1, C2, N1, N2, Cout, Cin);
            conv_b_tiled<32, 128, 2, 8, false><<<ga_, 256, 0, stream>>>(
                bufA, wb, gb, bb, outs[s], Cout, Cout, N1, Cout);
            continue;
        }

        // stages 0..2: 64x64 tile, 4x4/thread
        {
            int nsplit = nsA[s];
            int chunk = Cin / nsplit;
            dim3 grid(N1 / 64, Cout / 64, B * nsplit);
            if (nsplit == 1) {
                conv_a_tiled<64, 64, 4, 4, false><<<grid, 256, 0, stream>>>(
                    f[3 - s], x2, idxS, wSb, wa, ga, ba, bufA, C1, C2, N1, N2, Cout, chunk);
            } else {
                conv_a_tiled<64, 64, 4, 4, true><<<grid, 256, 0, stream>>>(
                    f[3 - s], x2, idxS, wSb, wa, ga, ba, gpart, C1, C2, N1, N2, Cout, chunk);
                int total4 = B * Cout * N1 / 4;
                reduce_bn_relu_kernel<<<(total4 + 255) / 256, 256, 0, stream>>>(
                    gpart, ga, ba, bufA, Cout, N1, total4, nsplit, total4);
            }
        }
        {
            int nsplit = nsB[s];
            int chunk = Cout / nsplit;
            dim3 grid(N1 / 64, Cout / 64, B * nsplit);
            if (nsplit == 1) {
                conv_b_tiled<64, 64, 4, 4, false><<<grid, 256, 0, stream>>>(
                    bufA, wb, gb, bb, outs[s], Cout, Cout, N1, chunk);
            } else {
                conv_b_tiled<64, 64, 4, 4, true><<<grid, 256, 0, stream>>>(
                    bufA, wb, gb, bb, gpart, Cout, Cout, N1, chunk);
                int total4 = B * Cout * N1 / 4;
                reduce_bn_relu_kernel<<<(total4 + 255) / 256, 256, 0, stream>>>(
                    gpart, gb, bb, outs[s], Cout, N1, total4, nsplit, total4);
            }
        }
    }
}